// Round 7
// baseline (968.256 us; speedup 1.0000x reference)
//
#include <hip/hip_runtime.h>
#include <cstdint>
#include <cstddef>

#define N_NODES 20000
#define N_EDGES 320000
#define NE_TOT  (N_EDGES + N_NODES)
#define BB 128
#define TT 200
#define EMB 128
#define GH 64
#define HEADS 4
#define LH 128
#define NSP 64
#define KF 136   // padded node-feature K (2 + 128 + 4 = 134 -> 136)

// ---------------------------------------------------------------- CSR build
__global__ void k_count(const int* __restrict__ ei, int* __restrict__ cnt) {
    int e = blockIdx.x * blockDim.x + threadIdx.x;
    if (e >= NE_TOT) return;
    int d = (e < N_EDGES) ? ei[N_EDGES + e] : (e - N_EDGES);
    atomicAdd(&cnt[d], 1);
}

__global__ __launch_bounds__(1024) void k_scan(const int* __restrict__ cnt, int* __restrict__ rs) {
    __shared__ int sd[1024];
    __shared__ int carry_s;
    int tid = threadIdx.x;
    if (tid == 0) carry_s = 0;
    __syncthreads();
    for (int base = 0; base < N_NODES; base += 1024) {
        int v = (base + tid < N_NODES) ? cnt[base + tid] : 0;
        int x = v;
        sd[tid] = x;
        __syncthreads();
        for (int off = 1; off < 1024; off <<= 1) {
            int t = (tid >= off) ? sd[tid - off] : 0;
            __syncthreads();
            x += t; sd[tid] = x;
            __syncthreads();
        }
        int carry = carry_s;
        if (base + tid < N_NODES) rs[base + tid] = carry + x - v;   // exclusive
        __syncthreads();
        if (tid == 0) carry_s = carry + sd[1023];
        __syncthreads();
    }
    if (tid == 0) rs[N_NODES] = carry_s;
}

__global__ void k_scatter(const int* __restrict__ ei, int* __restrict__ cursor, int* __restrict__ csr) {
    int e = blockIdx.x * blockDim.x + threadIdx.x;
    if (e >= NE_TOT) return;
    int s, d;
    if (e < N_EDGES) { s = ei[e]; d = ei[N_EDGES + e]; }
    else             { s = d = e - N_EDGES; }
    int pos = atomicAdd(&cursor[d], 1);
    csr[pos] = s;
}

// ---------------------------------------------------------------- feature build
__global__ void k_build_nf(const float* __restrict__ xc, const float* __restrict__ tf,
                           const float* __restrict__ ne, float* __restrict__ nf) {
    int n = blockIdx.x, j = threadIdx.x;
    if (j >= KF) return;
    float v = 0.f;
    if (j < 2)        v = xc[n * 2 + j];
    else if (j < 130) v = ne[n * 128 + (j - 2)];
    else if (j < 134) v = tf[n * 4 + (j - 130)];
    nf[(size_t)n * KF + j] = v;
}

__global__ void k_build_w1p(const float* __restrict__ W, float* __restrict__ Wp) {
    int k = blockIdx.x, n = threadIdx.x;
    Wp[k * 256 + n] = (k < 134) ? W[k * 256 + n] : 0.f;
}

__global__ void k_transpose512x128(const float* __restrict__ W, float* __restrict__ WT) {
    int idx = blockIdx.x * blockDim.x + threadIdx.x;
    if (idx >= 512 * 128) return;
    int g = idx & 511, k = idx >> 9;
    WT[k * 512 + g] = W[g * 128 + k];
}

// ---------------------------------------------------------------- generic f32 GEMM
// v6: BM=BN=128, BK=8, 256 threads, 8x8 micro-tile (split 4+4 cols/rows so
// inner-loop b128 LDS reads are 2-way bank-aliased = free). FMA:ds_read_b128
// ratio 16:1 (vs 8:1 at 64-tile) -> VALU-bound, barriers amortized 4x.
// C[M,N] = A[M,K] @ B[K,N] (+bias[n]); optional row gather on A. K % 8 == 0.
__global__ __launch_bounds__(256) void k_gemm_f32(
    const float* __restrict__ A, const float* __restrict__ B, float* __restrict__ C,
    int M, int N, int K, const int* __restrict__ gather, const float* __restrict__ bias)
{
    __shared__ float As[8][132];
    __shared__ float Bs[8][132];
    int tid = threadIdx.x;
    int bm = blockIdx.y << 7, bn = blockIdx.x << 7;
    int tx = tid & 15, ty = tid >> 4;
    float acc[8][8] = {};
    // staging indices
    int am  = tid >> 1;             // 0..127  (A row within tile)
    int akq = (tid & 1) << 2;       // 0 or 4  (K quad)
    long arow = -1;
    if (bm + am < M) arow = gather ? gather[bm + am] : (bm + am);
    int bkk = tid >> 5;             // 0..7    (B k-row)
    int bn4 = (tid & 31) << 2;      // 0..124  (B col quad)
    for (int k0 = 0; k0 < K; k0 += 8) {
        // A stage: 128 rows x 8 k (transposed into As[k][m])
        float4 va = make_float4(0.f, 0.f, 0.f, 0.f);
        if (arow >= 0) va = *(const float4*)(A + (size_t)arow * K + k0 + akq);
        As[akq + 0][am] = va.x; As[akq + 1][am] = va.y;
        As[akq + 2][am] = va.z; As[akq + 3][am] = va.w;
        // B stage: 8 k x 128 n
        {
            int gn = bn + bn4;
            const float* brow = B + (size_t)(k0 + bkk) * N;
            float4 vb = make_float4(0.f, 0.f, 0.f, 0.f);
            if (gn + 3 < N) vb = *(const float4*)(brow + gn);
            else {
                if (gn + 0 < N) vb.x = brow[gn + 0];
                if (gn + 1 < N) vb.y = brow[gn + 1];
                if (gn + 2 < N) vb.z = brow[gn + 2];
                if (gn + 3 < N) vb.w = brow[gn + 3];
            }
            *(float4*)(&Bs[bkk][bn4]) = vb;
        }
        __syncthreads();
#pragma unroll
        for (int k = 0; k < 8; k++) {
            float4 a0 = *(const float4*)&As[k][ty * 4];
            float4 a1 = *(const float4*)&As[k][64 + ty * 4];
            float4 b0 = *(const float4*)&Bs[k][tx * 4];
            float4 b1 = *(const float4*)&Bs[k][64 + tx * 4];
            float av[8] = {a0.x, a0.y, a0.z, a0.w, a1.x, a1.y, a1.z, a1.w};
            float bv[8] = {b0.x, b0.y, b0.z, b0.w, b1.x, b1.y, b1.z, b1.w};
#pragma unroll
            for (int i = 0; i < 8; i++)
#pragma unroll
                for (int jj = 0; jj < 8; jj++)
                    acc[i][jj] += av[i] * bv[jj];
        }
        __syncthreads();
    }
#pragma unroll
    for (int i = 0; i < 8; i++) {
        int gm = bm + ((i < 4) ? (ty * 4 + i) : (64 + ty * 4 + i - 4));
        if (gm >= M) continue;
#pragma unroll
        for (int jj = 0; jj < 8; jj++) {
            int gn = bn + ((jj < 4) ? (tx * 4 + jj) : (64 + tx * 4 + jj - 4));
            if (gn >= N) continue;
            float r = acc[i][jj];
            if (bias) r += bias[gn];
            C[(size_t)gm * N + gn] = r;
        }
    }
}

// ---------------------------------------------------------------- GAT attention dots
// a_s[n*H+h] = sum_c h[n,h*C+c]*att_src[h*C+c]; one wave per (n,h)
template <int H, int C>
__global__ void k_attn_dots(const float* __restrict__ hm, const float* __restrict__ asrc,
                            const float* __restrict__ adst, float* __restrict__ a_s,
                            float* __restrict__ a_d) {
    int wave = (blockIdx.x * blockDim.x + threadIdx.x) >> 6;
    int lane = threadIdx.x & 63;
    if (wave >= N_NODES * H) return;
    int n = wave / H, h = wave - n * H;
    const float* row = hm + (size_t)n * (H * C) + h * C;
    float ps = 0.f, pd = 0.f;
#pragma unroll
    for (int c0 = 0; c0 < C; c0 += 64) {
        float v = row[c0 + lane];
        ps += v * asrc[h * C + c0 + lane];
        pd += v * adst[h * C + c0 + lane];
    }
#pragma unroll
    for (int off = 32; off > 0; off >>= 1) {
        ps += __shfl_down(ps, off);
        pd += __shfl_down(pd, off);
    }
    if (lane == 0) { a_s[wave] = ps; a_d[wave] = pd; }
}

// ---------------------------------------------------------------- GAT segment softmax + aggregate
// one block per dst node; H*C threads; pass1 max, pass2 exp-sum + weighted accumulate
template <int H, int C, bool DO_ELU>
__global__ void k_gat_aggregate(const float* __restrict__ hm, const float* __restrict__ a_s,
                                const float* __restrict__ a_d, const int* __restrict__ rs,
                                const int* __restrict__ csr, const float* __restrict__ bias,
                                float* __restrict__ out) {
    int d = blockIdx.x;
    int tid = threadIdx.x;
    int h = tid / C;
    int r0 = rs[d], r1 = rs[d + 1];
    float adv = a_d[d * H + h];
    float m = -1e30f;
    for (int j = r0; j < r1; j++) {
        int s = csr[j];
        float e = a_s[s * H + h] + adv;
        e = (e > 0.f) ? e : 0.2f * e;
        m = fmaxf(m, e);
    }
    float den = 0.f, acc = 0.f;
    for (int j = r0; j < r1; j++) {
        int s = csr[j];
        float e = a_s[s * H + h] + adv;
        e = (e > 0.f) ? e : 0.2f * e;
        float ex = __expf(e - m);
        den += ex;
        acc += ex * hm[(size_t)s * (H * C) + tid];
    }
    float r = acc / den + bias[tid];
    if (DO_ELU) r = (r > 0.f) ? r : expm1f(r);
    out[(size_t)d * (H * C) + tid] = r;
}

// ---------------------------------------------------------------- BiLSTM recurrence
__device__ __forceinline__ float sigmf(float x) { return 1.f / (1.f + __expf(-x)); }
__device__ __forceinline__ float tanhfast(float x) {
    x = fminf(fmaxf(x, -20.f), 20.f);
    float e = __expf(2.f * x);
    return (e - 1.f) / (e + 1.f);
}

// one block per (batch, direction).
// v4b (measured 189 us): split-K register blocking + raw s_barrier +
// lgkmcnt-only fences (no vmcnt drain at barriers), sched_barrier(0) pinning.
// Global xg prefetch and deferred lstm_out store stay in flight across
// barriers and drain under the next step's matvec.
__global__ __launch_bounds__(512, 2) void k_lstm(
    const float* __restrict__ xg_f, const float* __restrict__ xg_b,
    const float* __restrict__ whh_f, const float* __restrict__ whh_b,
    const int* __restrict__ lengths, float* __restrict__ lstm_out)
{
    int b = blockIdx.x & 127;
    int dir = blockIdx.x >> 7;
    int tid = threadIdx.x;
    int u = tid & 127;          // hidden unit
    int j = tid >> 7;           // K-slice index (wave-uniform)
    const float* whh = dir ? whh_b : whh_f;
    const float* xg  = dir ? xg_b  : xg_f;
    int L = lengths[b];
    // W registers: w4[m][q] = W_hh[(m*128+u)][j*32 + 4q .. +3]
    float4 w4[4][8];
#pragma unroll
    for (int m = 0; m < 4; m++) {
        const float4* wrow = (const float4*)(whh + (size_t)(m * LH + u) * LH + j * 32);
#pragma unroll
        for (int q = 0; q < 8; q++) w4[m][q] = wrow[q];
    }
    __shared__ float hbuf[LH];
    __shared__ float pbuf[4][4 * LH];   // [j][m*128+u]
    if (tid < LH) hbuf[tid] = 0.f;
    float c = 0.f;
    float hv = 0.f;                     // previous step's h (deferred store), tid<128
    // xg prefetch for t=0 (j==0 threads)
    float x0 = 0.f, x1 = 0.f, x2 = 0.f, x3 = 0.f;
    if (j == 0) {
        int tx0 = dir ? (L - 1) : 0;
        const float* xrow = xg + ((size_t)b * TT + tx0) * (4 * LH);
        x0 = xrow[u]; x1 = xrow[LH + u]; x2 = xrow[2 * LH + u]; x3 = xrow[3 * LH + u];
    }
    __syncthreads();   // one-time full sync (drains weight/x loads; fine)
    for (int t = 0; t < L; t++) {
        // deferred global store of h(t-1); drains under the matvec below
        if (j == 0 && t > 0) {
            int txp = dir ? (L - t) : (t - 1);
            lstm_out[((size_t)b * TT + txp) * (2 * LH) + dir * LH + u] = hv;
        }
        // issue next step's xg load; consumed at t+1's FMA init (full step to drain)
        float x0n = 0.f, x1n = 0.f, x2n = 0.f, x3n = 0.f;
        if (j == 0 && t + 1 < L) {
            int tx1 = dir ? (L - 2 - t) : (t + 1);
            const float* xrow = xg + ((size_t)b * TT + tx1) * (4 * LH);
            x0n = xrow[u]; x1n = xrow[LH + u]; x2n = xrow[2 * LH + u]; x3n = xrow[3 * LH + u];
        }
        // partial matvec over K-slice j (broadcast LDS reads)
        const float4* hp = (const float4*)(hbuf + j * 32);
        float4 h[8];
#pragma unroll
        for (int q = 0; q < 8; q++) h[q] = hp[q];
        float a0 = x0, a1 = x1, a2 = x2, a3 = x3;   // zeros for j!=0
#pragma unroll
        for (int q = 0; q < 8; q++) {
            float4 hq = h[q];
            a0 += w4[0][q].x * hq.x + w4[0][q].y * hq.y + w4[0][q].z * hq.z + w4[0][q].w * hq.w;
            a1 += w4[1][q].x * hq.x + w4[1][q].y * hq.y + w4[1][q].z * hq.z + w4[1][q].w * hq.w;
            a2 += w4[2][q].x * hq.x + w4[2][q].y * hq.y + w4[2][q].z * hq.z + w4[2][q].w * hq.w;
            a3 += w4[3][q].x * hq.x + w4[3][q].y * hq.y + w4[3][q].z * hq.z + w4[3][q].w * hq.w;
        }
        pbuf[j][0 * LH + u] = a0;
        pbuf[j][1 * LH + u] = a1;
        pbuf[j][2 * LH + u] = a2;
        pbuf[j][3 * LH + u] = a3;
        // LDS-only fence + raw barrier (no vmcnt drain)
        asm volatile("s_waitcnt lgkmcnt(0)" ::: "memory");
        __builtin_amdgcn_sched_barrier(0);
        __builtin_amdgcn_s_barrier();
        // ---- phase 2: reduce + gates + state update (2 waves) ----
        if (tid < LH) {
            float gi = (pbuf[0][0 * LH + u] + pbuf[1][0 * LH + u]) + (pbuf[2][0 * LH + u] + pbuf[3][0 * LH + u]);
            float gf = (pbuf[0][1 * LH + u] + pbuf[1][1 * LH + u]) + (pbuf[2][1 * LH + u] + pbuf[3][1 * LH + u]);
            float gG = (pbuf[0][2 * LH + u] + pbuf[1][2 * LH + u]) + (pbuf[2][2 * LH + u] + pbuf[3][2 * LH + u]);
            float go = (pbuf[0][3 * LH + u] + pbuf[1][3 * LH + u]) + (pbuf[2][3 * LH + u] + pbuf[3][3 * LH + u]);
            float ig = sigmf(gi);
            float fg = sigmf(gf);
            float gg = tanhfast(gG);
            float og = sigmf(go);
            c = fg * c + ig * gg;
            hv = og * tanhfast(c);
            hbuf[u] = hv;    // safe: all phase-1 reads completed before barrier A
        }
        asm volatile("s_waitcnt lgkmcnt(0)" ::: "memory");
        __builtin_amdgcn_sched_barrier(0);
        __builtin_amdgcn_s_barrier();
        x0 = x0n; x1 = x1n; x2 = x2n; x3 = x3n;
    }
    // epilogue: store the final step's h
    if (j == 0) {
        int txp = dir ? 0 : (L - 1);
        lstm_out[((size_t)b * TT + txp) * (2 * LH) + dir * LH + u] = hv;
    }
}

// ---------------------------------------------------------------- masked attention pooling (both pools fused)
__global__ __launch_bounds__(256) void k_attnpool(
    const float* __restrict__ lo, const int* __restrict__ lengths,
    const float* __restrict__ wn, const float* __restrict__ bn,
    const float* __restrict__ wsp, const float* __restrict__ bsp,
    float* __restrict__ ctxn, float* __restrict__ ctxs)
{
    int b = blockIdx.x;
    int tid = threadIdx.x;
    int L = lengths[b];
    __shared__ float sn[TT], ss[TT];
    __shared__ float red[256];
    int wv = tid >> 6, lane = tid & 63;
    for (int t = wv; t < L; t += 4) {
        const float* row = lo + ((size_t)b * TT + t) * (2 * LH);
        float pn = 0.f, ps = 0.f;
#pragma unroll
        for (int c0 = 0; c0 < 256; c0 += 64) {
            float v = row[c0 + lane];
            pn += v * wn[c0 + lane];
            ps += v * wsp[c0 + lane];
        }
#pragma unroll
        for (int off = 32; off > 0; off >>= 1) {
            pn += __shfl_down(pn, off);
            ps += __shfl_down(ps, off);
        }
        if (lane == 0) { sn[t] = pn + bn[0]; ss[t] = ps + bsp[0]; }
    }
    __syncthreads();
    float vn = (tid < L) ? sn[tid] : -1e30f;
    float vs = (tid < L) ? ss[tid] : -1e30f;
    red[tid] = vn; __syncthreads();
    for (int s = 128; s > 0; s >>= 1) { if (tid < s) red[tid] = fmaxf(red[tid], red[tid + s]); __syncthreads(); }
    float mn = red[0]; __syncthreads();
    red[tid] = vs; __syncthreads();
    for (int s = 128; s > 0; s >>= 1) { if (tid < s) red[tid] = fmaxf(red[tid], red[tid + s]); __syncthreads(); }
    float ms = red[0]; __syncthreads();
    float en = (tid < L) ? __expf(vn - mn) : 0.f;
    float es = (tid < L) ? __expf(vs - ms) : 0.f;
    red[tid] = en; __syncthreads();
    for (int s = 128; s > 0; s >>= 1) { if (tid < s) red[tid] += red[tid + s]; __syncthreads(); }
    float dn = red[0]; __syncthreads();
    red[tid] = es; __syncthreads();
    for (int s = 128; s > 0; s >>= 1) { if (tid < s) red[tid] += red[tid + s]; __syncthreads(); }
    float dsum = red[0]; __syncthreads();
    if (tid < L) { sn[tid] = en / dn; ss[tid] = es / dsum; }
    __syncthreads();
    float an = 0.f, asv = 0.f;
    for (int t = 0; t < L; t++) {
        float v = lo[((size_t)b * TT + t) * (2 * LH) + tid];
        an += sn[t] * v;
        asv += ss[t] * v;
    }
    ctxn[b * (2 * LH) + tid] = an;
    ctxs[b * (2 * LH) + tid] = asv;
}

// ---------------------------------------------------------------- launch
extern "C" void kernel_launch(void* const* d_in, const int* in_sizes, int n_in,
                              void* d_out, int out_size, void* d_ws, size_t ws_size,
                              hipStream_t stream) {
    (void)in_sizes; (void)n_in; (void)out_size; (void)ws_size;
    const float* x_coords = (const float*)d_in[0];
    const float* temporal = (const float*)d_in[1];
    const float* node_emb = (const float*)d_in[2];
    const float* gat1_W   = (const float*)d_in[3];
    const float* gat1_as  = (const float*)d_in[4];
    const float* gat1_ad  = (const float*)d_in[5];
    const float* gat1_b   = (const float*)d_in[6];
    const float* gat2_W   = (const float*)d_in[7];
    const float* gat2_as  = (const float*)d_in[8];
    const float* gat2_ad  = (const float*)d_in[9];
    const float* gat2_b   = (const float*)d_in[10];
    const float* w_ih_f   = (const float*)d_in[11];
    const float* w_hh_f   = (const float*)d_in[12];
    const float* b_f      = (const float*)d_in[13];
    const float* w_ih_b   = (const float*)d_in[14];
    const float* w_hh_b   = (const float*)d_in[15];
    const float* b_b      = (const float*)d_in[16];
    const float* attn_n_w = (const float*)d_in[17];
    const float* attn_n_b = (const float*)d_in[18];
    const float* attn_s_w = (const float*)d_in[19];
    const float* attn_s_b = (const float*)d_in[20];
    const float* fc_n_W   = (const float*)d_in[21];
    const float* fc_n_b   = (const float*)d_in[22];
    const float* fc_s_W   = (const float*)d_in[23];
    const float* fc_s_b   = (const float*)d_in[24];
    const int*   edge_idx = (const int*)d_in[25];
    const int*   seq      = (const int*)d_in[26];
    const int*   lengths  = (const int*)d_in[27];

    char* ws = (char*)d_ws;
    size_t off = 0;
    auto alloc = [&](size_t bytes) -> char* {
        char* p = ws + off;
        off += (bytes + 255) & ~(size_t)255;
        return p;
    };
    int*   cnt      = (int*)alloc((size_t)N_NODES * 4);
    int*   rowstart = (int*)alloc((size_t)(N_NODES + 1) * 4);
    int*   cursor   = (int*)alloc((size_t)N_NODES * 4);
    int*   csr      = (int*)alloc((size_t)NE_TOT * 4);
    float* z2       = (float*)alloc((size_t)N_NODES * EMB * 4);
    float* lstm_o   = (float*)alloc((size_t)BB * TT * 2 * LH * 4);
    float* ctxn     = (float*)alloc((size_t)BB * 2 * LH * 4);
    float* ctxs     = (float*)alloc((size_t)BB * 2 * LH * 4);
    float* wTf      = (float*)alloc((size_t)128 * 512 * 4);
    float* wTb      = (float*)alloc((size_t)128 * 512 * 4);
    // reused region P4: GAT scratch first, then xg buffers (GAT scratch dead by then)
    float* nf  = (float*)(ws + off);
    float* w1p = nf + (size_t)N_NODES * KF;
    float* h1  = w1p + (size_t)KF * 256;
    float* as1 = h1 + (size_t)N_NODES * 256;
    float* ad1 = as1 + (size_t)N_NODES * 4;
    float* z1  = ad1 + (size_t)N_NODES * 4;
    float* h2  = z1 + (size_t)N_NODES * 256;
    float* as2 = h2 + (size_t)N_NODES * 128;
    float* ad2 = as2 + (size_t)N_NODES;
    float* xgf = (float*)(ws + off);               // overlays nf..ad2
    float* xgb = xgf + (size_t)BB * TT * 4 * LH;

    // --- CSR build (shared by both GAT layers)
    hipMemsetAsync(cnt, 0, (size_t)N_NODES * 4, stream);
    k_count<<<(NE_TOT + 255) / 256, 256, 0, stream>>>(edge_idx, cnt);
    k_scan<<<1, 1024, 0, stream>>>(cnt, rowstart);
    hipMemcpyAsync(cursor, rowstart, (size_t)N_NODES * 4, hipMemcpyDeviceToDevice, stream);
    k_scatter<<<(NE_TOT + 255) / 256, 256, 0, stream>>>(edge_idx, cursor, csr);

    // --- GAT layer 1
    k_build_nf<<<N_NODES, 192, 0, stream>>>(x_coords, temporal, node_emb, nf);
    k_build_w1p<<<KF, 256, 0, stream>>>(gat1_W, w1p);
    {
        dim3 g((256 + 127) / 128, (N_NODES + 127) / 128);
        k_gemm_f32<<<g, 256, 0, stream>>>(nf, w1p, h1, N_NODES, 256, KF, nullptr, nullptr);
    }
    k_attn_dots<HEADS, GH><<<(N_NODES * HEADS + 3) / 4, 256, 0, stream>>>(h1, gat1_as, gat1_ad, as1, ad1);
    k_gat_aggregate<HEADS, GH, true><<<N_NODES, 256, 0, stream>>>(h1, as1, ad1, rowstart, csr, gat1_b, z1);

    // --- GAT layer 2
    {
        dim3 g(1, (N_NODES + 127) / 128);
        k_gemm_f32<<<g, 256, 0, stream>>>(z1, gat2_W, h2, N_NODES, 128, 256, nullptr, nullptr);
    }
    k_attn_dots<1, EMB><<<(N_NODES + 3) / 4, 256, 0, stream>>>(h2, gat2_as, gat2_ad, as2, ad2);
    k_gat_aggregate<1, EMB, false><<<N_NODES, 128, 0, stream>>>(h2, as2, ad2, rowstart, csr, gat2_b, z2);

    // --- x-gate precompute (gather z2[seq] fused into GEMM A-load)
    k_transpose512x128<<<(512 * 128 + 255) / 256, 256, 0, stream>>>(w_ih_f, wTf);
    k_transpose512x128<<<(512 * 128 + 255) / 256, 256, 0, stream>>>(w_ih_b, wTb);
    {
        dim3 g((512 + 127) / 128, (BB * TT + 127) / 128);
        k_gemm_f32<<<g, 256, 0, stream>>>(z2, wTf, xgf, BB * TT, 512, 128, seq, b_f);
        k_gemm_f32<<<g, 256, 0, stream>>>(z2, wTb, xgb, BB * TT, 512, 128, seq, b_b);
    }

    // --- BiLSTM recurrence (persistent per (batch,dir), early-exit at lengths[b])
    k_lstm<<<256, 512, 0, stream>>>(xgf, xgb, w_hh_f, w_hh_b, lengths, lstm_o);

    // --- attention pooling (both pools)
    k_attnpool<<<BB, 256, 0, stream>>>(lstm_o, lengths, attn_n_w, attn_n_b, attn_s_w, attn_s_b, ctxn, ctxs);

    // --- output heads
    float* out_node = (float*)d_out;
    float* out_sp   = out_node + (size_t)BB * N_NODES;
    {
        dim3 g((N_NODES + 127) / 128, 1);
        k_gemm_f32<<<g, 256, 0, stream>>>(ctxn, fc_n_W, out_node, BB, N_NODES, 256, nullptr, fc_n_b);
    }
    {
        dim3 g(1, 1);
        k_gemm_f32<<<g, 256, 0, stream>>>(ctxs, fc_s_W, out_sp, BB, NSP, 256, nullptr, fc_s_b);
    }
}

// Round 8
// 791.504 us; speedup vs baseline: 1.2233x; 1.2233x over previous
//
#include <hip/hip_runtime.h>
#include <cstdint>
#include <cstddef>

#define N_NODES 20000
#define N_EDGES 320000
#define NE_TOT  (N_EDGES + N_NODES)
#define BB 128
#define TT 200
#define EMB 128
#define GH 64
#define HEADS 4
#define LH 128
#define NSP 64
#define KF 136   // padded node-feature K (2 + 128 + 4 = 134 -> 136)

// ---------------------------------------------------------------- CSR build
__global__ void k_count(const int* __restrict__ ei, int* __restrict__ cnt) {
    int e = blockIdx.x * blockDim.x + threadIdx.x;
    if (e >= NE_TOT) return;
    int d = (e < N_EDGES) ? ei[N_EDGES + e] : (e - N_EDGES);
    atomicAdd(&cnt[d], 1);
}

__global__ __launch_bounds__(1024) void k_scan(const int* __restrict__ cnt, int* __restrict__ rs) {
    __shared__ int sd[1024];
    __shared__ int carry_s;
    int tid = threadIdx.x;
    if (tid == 0) carry_s = 0;
    __syncthreads();
    for (int base = 0; base < N_NODES; base += 1024) {
        int v = (base + tid < N_NODES) ? cnt[base + tid] : 0;
        int x = v;
        sd[tid] = x;
        __syncthreads();
        for (int off = 1; off < 1024; off <<= 1) {
            int t = (tid >= off) ? sd[tid - off] : 0;
            __syncthreads();
            x += t; sd[tid] = x;
            __syncthreads();
        }
        int carry = carry_s;
        if (base + tid < N_NODES) rs[base + tid] = carry + x - v;   // exclusive
        __syncthreads();
        if (tid == 0) carry_s = carry + sd[1023];
        __syncthreads();
    }
    if (tid == 0) rs[N_NODES] = carry_s;
}

__global__ void k_scatter(const int* __restrict__ ei, int* __restrict__ cursor, int* __restrict__ csr) {
    int e = blockIdx.x * blockDim.x + threadIdx.x;
    if (e >= NE_TOT) return;
    int s, d;
    if (e < N_EDGES) { s = ei[e]; d = ei[N_EDGES + e]; }
    else             { s = d = e - N_EDGES; }
    int pos = atomicAdd(&cursor[d], 1);
    csr[pos] = s;
}

// ---------------------------------------------------------------- feature build
__global__ void k_build_nf(const float* __restrict__ xc, const float* __restrict__ tf,
                           const float* __restrict__ ne, float* __restrict__ nf) {
    int n = blockIdx.x, j = threadIdx.x;
    if (j >= KF) return;
    float v = 0.f;
    if (j < 2)        v = xc[n * 2 + j];
    else if (j < 130) v = ne[n * 128 + (j - 2)];
    else if (j < 134) v = tf[n * 4 + (j - 130)];
    nf[(size_t)n * KF + j] = v;
}

__global__ void k_build_w1p(const float* __restrict__ W, float* __restrict__ Wp) {
    int k = blockIdx.x, n = threadIdx.x;
    Wp[k * 256 + n] = (k < 134) ? W[k * 256 + n] : 0.f;
}

// transpose W[512][128] -> WT[k][1024] columns [colOff, colOff+512)
__global__ void k_transpose_cat(const float* __restrict__ W, float* __restrict__ WT, int colOff) {
    int idx = blockIdx.x * blockDim.x + threadIdx.x;
    if (idx >= 512 * 128) return;
    int g = idx & 511, k = idx >> 9;
    WT[k * 1024 + colOff + g] = W[g * 128 + k];
}

__global__ void k_build_bcat(const float* __restrict__ bf, const float* __restrict__ bb,
                             float* __restrict__ bcat) {
    int t = threadIdx.x;   // 512 threads
    bcat[t] = bf[t];
    bcat[512 + t] = bb[t];
}

// ---------------------------------------------------------------- length prefix + row maps
__global__ void k_len_prefix(const int* __restrict__ lengths, int* __restrict__ loff) {
    if (threadIdx.x == 0) {
        int acc = 0;
        for (int b = 0; b < BB; b++) { loff[b] = acc; acc += lengths[b]; }
        loff[BB] = acc;
    }
}

__global__ void k_build_rowmap(const int* __restrict__ lengths, const int* __restrict__ loff,
                               const int* __restrict__ seq, int* __restrict__ rowsrc,
                               int* __restrict__ rowdst) {
    int idx = blockIdx.x * blockDim.x + threadIdx.x;
    if (idx >= BB * TT) return;
    int b = idx / TT, t = idx - b * TT;
    if (t >= lengths[b]) return;
    int pos = loff[b] + t;
    rowsrc[pos] = seq[idx];       // A-gather: z2 row
    rowdst[pos] = idx;            // C-scatter: (b*TT+t)
}

// ---------------------------------------------------------------- generic f32 GEMM (proven 64-tile)
// C[M,N] = A[M,K] @ B[K,N] (+bias[n]); optional row gather on A.
// Requires K % 8 == 0. BM=BN=64, BK=8, 256 threads, 4x4 micro-tile.
__global__ __launch_bounds__(256) void k_gemm_f32(
    const float* __restrict__ A, const float* __restrict__ B, float* __restrict__ C,
    int M, int N, int K, const int* __restrict__ gather, const float* __restrict__ bias)
{
    __shared__ float As[8][68];
    __shared__ float Bs[8][68];
    int tid = threadIdx.x;
    int bm = blockIdx.y << 6, bn = blockIdx.x << 6;
    int tm = (tid >> 4) << 2, tn = (tid & 15) << 2;
    float acc[4][4] = {};
    for (int k0 = 0; k0 < K; k0 += 8) {
        if (tid < 128) {
            int m = tid >> 1, kq = (tid & 1) << 2;
            int gm = bm + m;
            float4 v = make_float4(0.f, 0.f, 0.f, 0.f);
            if (gm < M) {
                int row = gather ? gather[gm] : gm;
                v = *(const float4*)(A + (size_t)row * K + k0 + kq);
            }
            As[kq + 0][m] = v.x; As[kq + 1][m] = v.y;
            As[kq + 2][m] = v.z; As[kq + 3][m] = v.w;
        } else {
            int t2 = tid - 128;
            int kk = t2 >> 4, n4 = (t2 & 15) << 2;
            int gn = bn + n4;
            float4 v = make_float4(0.f, 0.f, 0.f, 0.f);
            const float* brow = B + (size_t)(k0 + kk) * N;
            if (gn + 3 < N) v = *(const float4*)(brow + gn);
            else {
                if (gn + 0 < N) v.x = brow[gn + 0];
                if (gn + 1 < N) v.y = brow[gn + 1];
                if (gn + 2 < N) v.z = brow[gn + 2];
                if (gn + 3 < N) v.w = brow[gn + 3];
            }
            *(float4*)(&Bs[kk][n4]) = v;
        }
        __syncthreads();
#pragma unroll
        for (int k = 0; k < 8; k++) {
            float4 av = *(const float4*)&As[k][tm];
            float4 bv = *(const float4*)&Bs[k][tn];
            acc[0][0] += av.x * bv.x; acc[0][1] += av.x * bv.y; acc[0][2] += av.x * bv.z; acc[0][3] += av.x * bv.w;
            acc[1][0] += av.y * bv.x; acc[1][1] += av.y * bv.y; acc[1][2] += av.y * bv.z; acc[1][3] += av.y * bv.w;
            acc[2][0] += av.z * bv.x; acc[2][1] += av.z * bv.y; acc[2][2] += av.z * bv.z; acc[2][3] += av.z * bv.w;
            acc[3][0] += av.w * bv.x; acc[3][1] += av.w * bv.y; acc[3][2] += av.w * bv.z; acc[3][3] += av.w * bv.w;
        }
        __syncthreads();
    }
#pragma unroll
    for (int i = 0; i < 4; i++) {
        int gm = bm + tm + i;
        if (gm >= M) continue;
#pragma unroll
        for (int j = 0; j < 4; j++) {
            int gn = bn + tn + j;
            if (gn >= N) continue;
            float r = acc[i][j];
            if (bias) r += bias[gn];
            C[(size_t)gm * N + gn] = r;
        }
    }
}

// 64-tile GEMM, compacted-row variant: M read from device (loff[BB]), A rows
// gathered via rowsrc[], C rows scattered via rowdst[]. N must be mult of 4.
__global__ __launch_bounds__(256) void k_gemm_f32_rs(
    const float* __restrict__ A, const float* __restrict__ B, float* __restrict__ C,
    const int* __restrict__ Mdev, int N, int K,
    const int* __restrict__ rowsrc, const int* __restrict__ rowdst,
    const float* __restrict__ bias)
{
    int M = Mdev[BB];
    int bm = blockIdx.y << 6, bn = blockIdx.x << 6;
    if (bm >= M) return;          // uniform early-exit (before any barrier)
    __shared__ float As[8][68];
    __shared__ float Bs[8][68];
    int tid = threadIdx.x;
    int tm = (tid >> 4) << 2, tn = (tid & 15) << 2;
    float acc[4][4] = {};
    for (int k0 = 0; k0 < K; k0 += 8) {
        if (tid < 128) {
            int m = tid >> 1, kq = (tid & 1) << 2;
            int gm = bm + m;
            float4 v = make_float4(0.f, 0.f, 0.f, 0.f);
            if (gm < M) {
                int row = rowsrc[gm];
                v = *(const float4*)(A + (size_t)row * K + k0 + kq);
            }
            As[kq + 0][m] = v.x; As[kq + 1][m] = v.y;
            As[kq + 2][m] = v.z; As[kq + 3][m] = v.w;
        } else {
            int t2 = tid - 128;
            int kk = t2 >> 4, n4 = (t2 & 15) << 2;
            int gn = bn + n4;
            const float* brow = B + (size_t)(k0 + kk) * N;
            *(float4*)(&Bs[kk][n4]) = *(const float4*)(brow + gn);
        }
        __syncthreads();
#pragma unroll
        for (int k = 0; k < 8; k++) {
            float4 av = *(const float4*)&As[k][tm];
            float4 bv = *(const float4*)&Bs[k][tn];
            acc[0][0] += av.x * bv.x; acc[0][1] += av.x * bv.y; acc[0][2] += av.x * bv.z; acc[0][3] += av.x * bv.w;
            acc[1][0] += av.y * bv.x; acc[1][1] += av.y * bv.y; acc[1][2] += av.y * bv.z; acc[1][3] += av.y * bv.w;
            acc[2][0] += av.z * bv.x; acc[2][1] += av.z * bv.y; acc[2][2] += av.z * bv.z; acc[2][3] += av.z * bv.w;
            acc[3][0] += av.w * bv.x; acc[3][1] += av.w * bv.y; acc[3][2] += av.w * bv.z; acc[3][3] += av.w * bv.w;
        }
        __syncthreads();
    }
#pragma unroll
    for (int i = 0; i < 4; i++) {
        int gm = bm + tm + i;
        if (gm >= M) continue;
        size_t crow = (size_t)rowdst[gm] * N;
#pragma unroll
        for (int j = 0; j < 4; j++) {
            int gn = bn + tn + j;
            float r = acc[i][j] + bias[gn];
            C[crow + gn] = r;
        }
    }
}

// ---------------------------------------------------------------- GAT attention dots
// a_s[n*H+h] = sum_c h[n,h*C+c]*att_src[h*C+c]; one wave per (n,h)
template <int H, int C>
__global__ void k_attn_dots(const float* __restrict__ hm, const float* __restrict__ asrc,
                            const float* __restrict__ adst, float* __restrict__ a_s,
                            float* __restrict__ a_d) {
    int wave = (blockIdx.x * blockDim.x + threadIdx.x) >> 6;
    int lane = threadIdx.x & 63;
    if (wave >= N_NODES * H) return;
    int n = wave / H, h = wave - n * H;
    const float* row = hm + (size_t)n * (H * C) + h * C;
    float ps = 0.f, pd = 0.f;
#pragma unroll
    for (int c0 = 0; c0 < C; c0 += 64) {
        float v = row[c0 + lane];
        ps += v * asrc[h * C + c0 + lane];
        pd += v * adst[h * C + c0 + lane];
    }
#pragma unroll
    for (int off = 32; off > 0; off >>= 1) {
        ps += __shfl_down(ps, off);
        pd += __shfl_down(pd, off);
    }
    if (lane == 0) { a_s[wave] = ps; a_d[wave] = pd; }
}

// ---------------------------------------------------------------- GAT segment softmax + aggregate
// one block per dst node; H*C threads; pass1 max, pass2 exp-sum + weighted accumulate
template <int H, int C, bool DO_ELU>
__global__ void k_gat_aggregate(const float* __restrict__ hm, const float* __restrict__ a_s,
                                const float* __restrict__ a_d, const int* __restrict__ rs,
                                const int* __restrict__ csr, const float* __restrict__ bias,
                                float* __restrict__ out) {
    int d = blockIdx.x;
    int tid = threadIdx.x;
    int h = tid / C;
    int r0 = rs[d], r1 = rs[d + 1];
    float adv = a_d[d * H + h];
    float m = -1e30f;
    for (int j = r0; j < r1; j++) {
        int s = csr[j];
        float e = a_s[s * H + h] + adv;
        e = (e > 0.f) ? e : 0.2f * e;
        m = fmaxf(m, e);
    }
    float den = 0.f, acc = 0.f;
    for (int j = r0; j < r1; j++) {
        int s = csr[j];
        float e = a_s[s * H + h] + adv;
        e = (e > 0.f) ? e : 0.2f * e;
        float ex = __expf(e - m);
        den += ex;
        acc += ex * hm[(size_t)s * (H * C) + tid];
    }
    float r = acc / den + bias[tid];
    if (DO_ELU) r = (r > 0.f) ? r : expm1f(r);
    out[(size_t)d * (H * C) + tid] = r;
}

// ---------------------------------------------------------------- BiLSTM recurrence
__device__ __forceinline__ float sigmf(float x) { return 1.f / (1.f + __expf(-x)); }
__device__ __forceinline__ float tanhfast(float x) {
    x = fminf(fmaxf(x, -20.f), 20.f);
    float e = __expf(2.f * x);
    return (e - 1.f) / (e + 1.f);
}

// one block per (batch, direction).
// v4b (measured 189 us): split-K register blocking + raw s_barrier +
// lgkmcnt-only fences (no vmcnt drain at barriers), sched_barrier(0) pinning.
// Now reads fused xgcat (stride 1024, dir-half offset 512).
__global__ __launch_bounds__(512, 2) void k_lstm(
    const float* __restrict__ xgcat,
    const float* __restrict__ whh_f, const float* __restrict__ whh_b,
    const int* __restrict__ lengths, float* __restrict__ lstm_out)
{
    int b = blockIdx.x & 127;
    int dir = blockIdx.x >> 7;
    int tid = threadIdx.x;
    int u = tid & 127;          // hidden unit
    int j = tid >> 7;           // K-slice index (wave-uniform)
    const float* whh = dir ? whh_b : whh_f;
    const float* xg = xgcat + (dir << 9);   // half offset within 1024-stride rows
    int L = lengths[b];
    // W registers: w4[m][q] = W_hh[(m*128+u)][j*32 + 4q .. +3]
    float4 w4[4][8];
#pragma unroll
    for (int m = 0; m < 4; m++) {
        const float4* wrow = (const float4*)(whh + (size_t)(m * LH + u) * LH + j * 32);
#pragma unroll
        for (int q = 0; q < 8; q++) w4[m][q] = wrow[q];
    }
    __shared__ float hbuf[LH];
    __shared__ float pbuf[4][4 * LH];   // [j][m*128+u]
    if (tid < LH) hbuf[tid] = 0.f;
    float c = 0.f;
    float hv = 0.f;                     // previous step's h (deferred store), tid<128
    // xg prefetch for t=0 (j==0 threads)
    float x0 = 0.f, x1 = 0.f, x2 = 0.f, x3 = 0.f;
    if (j == 0) {
        int tx0 = dir ? (L - 1) : 0;
        const float* xrow = xg + ((size_t)(b * TT + tx0) << 10);
        x0 = xrow[u]; x1 = xrow[LH + u]; x2 = xrow[2 * LH + u]; x3 = xrow[3 * LH + u];
    }
    __syncthreads();   // one-time full sync (drains weight/x loads; fine)
    for (int t = 0; t < L; t++) {
        // deferred global store of h(t-1); drains under the matvec below
        if (j == 0 && t > 0) {
            int txp = dir ? (L - t) : (t - 1);
            lstm_out[((size_t)b * TT + txp) * (2 * LH) + dir * LH + u] = hv;
        }
        // issue next step's xg load; consumed at t+1's FMA init (full step to drain)
        float x0n = 0.f, x1n = 0.f, x2n = 0.f, x3n = 0.f;
        if (j == 0 && t + 1 < L) {
            int tx1 = dir ? (L - 2 - t) : (t + 1);
            const float* xrow = xg + ((size_t)(b * TT + tx1) << 10);
            x0n = xrow[u]; x1n = xrow[LH + u]; x2n = xrow[2 * LH + u]; x3n = xrow[3 * LH + u];
        }
        // partial matvec over K-slice j (broadcast LDS reads)
        const float4* hp = (const float4*)(hbuf + j * 32);
        float4 h[8];
#pragma unroll
        for (int q = 0; q < 8; q++) h[q] = hp[q];
        float a0 = x0, a1 = x1, a2 = x2, a3 = x3;   // zeros for j!=0
#pragma unroll
        for (int q = 0; q < 8; q++) {
            float4 hq = h[q];
            a0 += w4[0][q].x * hq.x + w4[0][q].y * hq.y + w4[0][q].z * hq.z + w4[0][q].w * hq.w;
            a1 += w4[1][q].x * hq.x + w4[1][q].y * hq.y + w4[1][q].z * hq.z + w4[1][q].w * hq.w;
            a2 += w4[2][q].x * hq.x + w4[2][q].y * hq.y + w4[2][q].z * hq.z + w4[2][q].w * hq.w;
            a3 += w4[3][q].x * hq.x + w4[3][q].y * hq.y + w4[3][q].z * hq.z + w4[3][q].w * hq.w;
        }
        pbuf[j][0 * LH + u] = a0;
        pbuf[j][1 * LH + u] = a1;
        pbuf[j][2 * LH + u] = a2;
        pbuf[j][3 * LH + u] = a3;
        // LDS-only fence + raw barrier (no vmcnt drain)
        asm volatile("s_waitcnt lgkmcnt(0)" ::: "memory");
        __builtin_amdgcn_sched_barrier(0);
        __builtin_amdgcn_s_barrier();
        // ---- phase 2: reduce + gates + state update (2 waves) ----
        if (tid < LH) {
            float gi = (pbuf[0][0 * LH + u] + pbuf[1][0 * LH + u]) + (pbuf[2][0 * LH + u] + pbuf[3][0 * LH + u]);
            float gf = (pbuf[0][1 * LH + u] + pbuf[1][1 * LH + u]) + (pbuf[2][1 * LH + u] + pbuf[3][1 * LH + u]);
            float gG = (pbuf[0][2 * LH + u] + pbuf[1][2 * LH + u]) + (pbuf[2][2 * LH + u] + pbuf[3][2 * LH + u]);
            float go = (pbuf[0][3 * LH + u] + pbuf[1][3 * LH + u]) + (pbuf[2][3 * LH + u] + pbuf[3][3 * LH + u]);
            float ig = sigmf(gi);
            float fg = sigmf(gf);
            float gg = tanhfast(gG);
            float og = sigmf(go);
            c = fg * c + ig * gg;
            hv = og * tanhfast(c);
            hbuf[u] = hv;    // safe: all phase-1 reads completed before barrier A
        }
        asm volatile("s_waitcnt lgkmcnt(0)" ::: "memory");
        __builtin_amdgcn_sched_barrier(0);
        __builtin_amdgcn_s_barrier();
        x0 = x0n; x1 = x1n; x2 = x2n; x3 = x3n;
    }
    // epilogue: store the final step's h
    if (j == 0) {
        int txp = dir ? 0 : (L - 1);
        lstm_out[((size_t)b * TT + txp) * (2 * LH) + dir * LH + u] = hv;
    }
}

// ---------------------------------------------------------------- masked attention pooling (both pools fused)
__global__ __launch_bounds__(256) void k_attnpool(
    const float* __restrict__ lo, const int* __restrict__ lengths,
    const float* __restrict__ wn, const float* __restrict__ bn,
    const float* __restrict__ wsp, const float* __restrict__ bsp,
    float* __restrict__ ctxn, float* __restrict__ ctxs)
{
    int b = blockIdx.x;
    int tid = threadIdx.x;
    int L = lengths[b];
    __shared__ float sn[TT], ss[TT];
    __shared__ float red[256];
    int wv = tid >> 6, lane = tid & 63;
    for (int t = wv; t < L; t += 4) {
        const float* row = lo + ((size_t)b * TT + t) * (2 * LH);
        float pn = 0.f, ps = 0.f;
#pragma unroll
        for (int c0 = 0; c0 < 256; c0 += 64) {
            float v = row[c0 + lane];
            pn += v * wn[c0 + lane];
            ps += v * wsp[c0 + lane];
        }
#pragma unroll
        for (int off = 32; off > 0; off >>= 1) {
            pn += __shfl_down(pn, off);
            ps += __shfl_down(ps, off);
        }
        if (lane == 0) { sn[t] = pn + bn[0]; ss[t] = ps + bsp[0]; }
    }
    __syncthreads();
    float vn = (tid < L) ? sn[tid] : -1e30f;
    float vs = (tid < L) ? ss[tid] : -1e30f;
    red[tid] = vn; __syncthreads();
    for (int s = 128; s > 0; s >>= 1) { if (tid < s) red[tid] = fmaxf(red[tid], red[tid + s]); __syncthreads(); }
    float mn = red[0]; __syncthreads();
    red[tid] = vs; __syncthreads();
    for (int s = 128; s > 0; s >>= 1) { if (tid < s) red[tid] = fmaxf(red[tid], red[tid + s]); __syncthreads(); }
    float ms = red[0]; __syncthreads();
    float en = (tid < L) ? __expf(vn - mn) : 0.f;
    float es = (tid < L) ? __expf(vs - ms) : 0.f;
    red[tid] = en; __syncthreads();
    for (int s = 128; s > 0; s >>= 1) { if (tid < s) red[tid] += red[tid + s]; __syncthreads(); }
    float dn = red[0]; __syncthreads();
    red[tid] = es; __syncthreads();
    for (int s = 128; s > 0; s >>= 1) { if (tid < s) red[tid] += red[tid + s]; __syncthreads(); }
    float dsum = red[0]; __syncthreads();
    if (tid < L) { sn[tid] = en / dn; ss[tid] = es / dsum; }
    __syncthreads();
    float an = 0.f, asv = 0.f;
    for (int t = 0; t < L; t++) {
        float v = lo[((size_t)b * TT + t) * (2 * LH) + tid];
        an += sn[t] * v;
        asv += ss[t] * v;
    }
    ctxn[b * (2 * LH) + tid] = an;
    ctxs[b * (2 * LH) + tid] = asv;
}

// ---------------------------------------------------------------- launch
extern "C" void kernel_launch(void* const* d_in, const int* in_sizes, int n_in,
                              void* d_out, int out_size, void* d_ws, size_t ws_size,
                              hipStream_t stream) {
    (void)in_sizes; (void)n_in; (void)out_size; (void)ws_size;
    const float* x_coords = (const float*)d_in[0];
    const float* temporal = (const float*)d_in[1];
    const float* node_emb = (const float*)d_in[2];
    const float* gat1_W   = (const float*)d_in[3];
    const float* gat1_as  = (const float*)d_in[4];
    const float* gat1_ad  = (const float*)d_in[5];
    const float* gat1_b   = (const float*)d_in[6];
    const float* gat2_W   = (const float*)d_in[7];
    const float* gat2_as  = (const float*)d_in[8];
    const float* gat2_ad  = (const float*)d_in[9];
    const float* gat2_b   = (const float*)d_in[10];
    const float* w_ih_f   = (const float*)d_in[11];
    const float* w_hh_f   = (const float*)d_in[12];
    const float* b_f      = (const float*)d_in[13];
    const float* w_ih_b   = (const float*)d_in[14];
    const float* w_hh_b   = (const float*)d_in[15];
    const float* b_b      = (const float*)d_in[16];
    const float* attn_n_w = (const float*)d_in[17];
    const float* attn_n_b = (const float*)d_in[18];
    const float* attn_s_w = (const float*)d_in[19];
    const float* attn_s_b = (const float*)d_in[20];
    const float* fc_n_W   = (const float*)d_in[21];
    const float* fc_n_b   = (const float*)d_in[22];
    const float* fc_s_W   = (const float*)d_in[23];
    const float* fc_s_b   = (const float*)d_in[24];
    const int*   edge_idx = (const int*)d_in[25];
    const int*   seq      = (const int*)d_in[26];
    const int*   lengths  = (const int*)d_in[27];

    char* ws = (char*)d_ws;
    size_t off = 0;
    auto alloc = [&](size_t bytes) -> char* {
        char* p = ws + off;
        off += (bytes + 255) & ~(size_t)255;
        return p;
    };
    int*   cnt      = (int*)alloc((size_t)N_NODES * 4);
    int*   rowstart = (int*)alloc((size_t)(N_NODES + 1) * 4);
    int*   cursor   = (int*)alloc((size_t)N_NODES * 4);
    int*   csr      = (int*)alloc((size_t)NE_TOT * 4);
    float* z2       = (float*)alloc((size_t)N_NODES * EMB * 4);
    float* lstm_o   = (float*)alloc((size_t)BB * TT * 2 * LH * 4);
    float* ctxn     = (float*)alloc((size_t)BB * 2 * LH * 4);
    float* ctxs     = (float*)alloc((size_t)BB * 2 * LH * 4);
    float* wTcat    = (float*)alloc((size_t)128 * 1024 * 4);
    float* bcat     = (float*)alloc((size_t)1024 * 4);
    int*   loff     = (int*)alloc((size_t)(BB + 1) * 4);
    int*   rowsrc   = (int*)alloc((size_t)BB * TT * 4);
    int*   rowdst   = (int*)alloc((size_t)BB * TT * 4);
    // reused region P4: GAT scratch first, then xgcat (GAT scratch dead by then)
    float* nf  = (float*)(ws + off);
    float* w1p = nf + (size_t)N_NODES * KF;
    float* h1  = w1p + (size_t)KF * 256;
    float* as1 = h1 + (size_t)N_NODES * 256;
    float* ad1 = as1 + (size_t)N_NODES * 4;
    float* z1  = ad1 + (size_t)N_NODES * 4;
    float* h2  = z1 + (size_t)N_NODES * 256;
    float* as2 = h2 + (size_t)N_NODES * 128;
    float* ad2 = as2 + (size_t)N_NODES;
    float* xgcat = (float*)(ws + off);             // overlays nf..ad2; BB*TT*1024 floats

    // --- CSR build (shared by both GAT layers)
    hipMemsetAsync(cnt, 0, (size_t)N_NODES * 4, stream);
    k_count<<<(NE_TOT + 255) / 256, 256, 0, stream>>>(edge_idx, cnt);
    k_scan<<<1, 1024, 0, stream>>>(cnt, rowstart);
    hipMemcpyAsync(cursor, rowstart, (size_t)N_NODES * 4, hipMemcpyDeviceToDevice, stream);
    k_scatter<<<(NE_TOT + 255) / 256, 256, 0, stream>>>(edge_idx, cursor, csr);

    // --- row compaction for xg GEMM
    k_len_prefix<<<1, 64, 0, stream>>>(lengths, loff);
    k_build_rowmap<<<(BB * TT + 255) / 256, 256, 0, stream>>>(lengths, loff, seq, rowsrc, rowdst);

    // --- GAT layer 1
    k_build_nf<<<N_NODES, 192, 0, stream>>>(x_coords, temporal, node_emb, nf);
    k_build_w1p<<<KF, 256, 0, stream>>>(gat1_W, w1p);
    {
        dim3 g(4, (N_NODES + 63) / 64);
        k_gemm_f32<<<g, 256, 0, stream>>>(nf, w1p, h1, N_NODES, 256, KF, nullptr, nullptr);
    }
    k_attn_dots<HEADS, GH><<<(N_NODES * HEADS + 3) / 4, 256, 0, stream>>>(h1, gat1_as, gat1_ad, as1, ad1);
    k_gat_aggregate<HEADS, GH, true><<<N_NODES, 256, 0, stream>>>(h1, as1, ad1, rowstart, csr, gat1_b, z1);

    // --- GAT layer 2
    {
        dim3 g(2, (N_NODES + 63) / 64);
        k_gemm_f32<<<g, 256, 0, stream>>>(z1, gat2_W, h2, N_NODES, 128, 256, nullptr, nullptr);
    }
    k_attn_dots<1, EMB><<<(N_NODES + 3) / 4, 256, 0, stream>>>(h2, gat2_as, gat2_ad, as2, ad2);
    k_gat_aggregate<1, EMB, false><<<N_NODES, 128, 0, stream>>>(h2, as2, ad2, rowstart, csr, gat2_b, z2);

    // --- x-gate precompute: fused F+B GEMM over COMPACTED rows only
    k_transpose_cat<<<(512 * 128 + 255) / 256, 256, 0, stream>>>(w_ih_f, wTcat, 0);
    k_transpose_cat<<<(512 * 128 + 255) / 256, 256, 0, stream>>>(w_ih_b, wTcat, 512);
    k_build_bcat<<<1, 512, 0, stream>>>(b_f, b_b, bcat);
    {
        dim3 g(1024 / 64, (BB * TT + 63) / 64);   // surplus row-blocks exit early on Mdev
        k_gemm_f32_rs<<<g, 256, 0, stream>>>(z2, wTcat, xgcat, loff, 1024, 128, rowsrc, rowdst, bcat);
    }

    // --- BiLSTM recurrence (persistent per (batch,dir), early-exit at lengths[b])
    k_lstm<<<256, 512, 0, stream>>>(xgcat, w_hh_f, w_hh_b, lengths, lstm_o);

    // --- attention pooling (both pools)
    k_attnpool<<<BB, 256, 0, stream>>>(lstm_o, lengths, attn_n_w, attn_n_b, attn_s_w, attn_s_b, ctxn, ctxs);

    // --- output heads
    float* out_node = (float*)d_out;
    float* out_sp   = out_node + (size_t)BB * N_NODES;
    {
        dim3 g((N_NODES + 63) / 64, 2);
        k_gemm_f32<<<g, 256, 0, stream>>>(ctxn, fc_n_W, out_node, BB, N_NODES, 256, nullptr, fc_n_b);
    }
    {
        dim3 g(1, 2);
        k_gemm_f32<<<g, 256, 0, stream>>>(ctxs, fc_s_W, out_sp, BB, NSP, 256, nullptr, fc_s_b);
    }
}